// Round 1
// baseline (11915.292 us; speedup 1.0000x reference)
//
#include <hip/hip_runtime.h>

// ---------------- problem constants ----------------
#define CN0 100000
#define CN1 25000
#define CN2 6250
#define CE0 20000
#define CE1 5000
#define CE2 1250
#define CNNZ0 1600000
#define CNNZ1 400000
#define CNNZ2 100000
// D_IN = D_H = 128, D_OUT = 64

static inline int cdiv_i(long long a, long long b) { return (int)((a + b - 1) / b); }

// ---------------- degree / normalization kernels ----------------
__global__ __launch_bounds__(256) void k_degree2(const int* __restrict__ vi,
                                                 const int* __restrict__ ei,
                                                 float* __restrict__ dV,
                                                 float* __restrict__ dE, int nnz) {
  int i = blockIdx.x * 256 + threadIdx.x;
  if (i < nnz) {
    atomicAdd(dV + vi[i], 1.0f);
    atomicAdd(dE + ei[i], 1.0f);
  }
}

__global__ __launch_bounds__(256) void k_count(const int* __restrict__ idx,
                                               float* __restrict__ c, int n) {
  int i = blockIdx.x * 256 + threadIdx.x;
  if (i < n) atomicAdd(c + idx[i], 1.0f);
}

// mode 0: x>0 ? x^-1/2 : 0 ; mode 1: x>0 ? 1/x : 0
__global__ __launch_bounds__(256) void k_recip(float* __restrict__ x, int n, int mode) {
  int i = blockIdx.x * 256 + threadIdx.x;
  if (i < n) {
    float v = x[i];
    float r = 0.0f;
    if (v > 0.0f) r = (mode == 0) ? (1.0f / sqrtf(v)) : (1.0f / v);
    x[i] = r;
  }
}

// ---------------- scatter (segment-sum) kernel ----------------
// Y[dst[k]][:] += X[srcrow][:] * (scale ? scale[srcrow] : 1),  srcrow = src?src[k]:k
// D4 = D/4 (threads per nnz, each handles a float4)
__global__ __launch_bounds__(256) void k_scatter(const float* __restrict__ X,
                                                 const int* __restrict__ src,
                                                 const int* __restrict__ dst,
                                                 const float* __restrict__ scale,
                                                 float* __restrict__ Y,
                                                 long long nnz, int D4) {
  long long tid = (long long)blockIdx.x * 256 + threadIdx.x;
  long long total = nnz * (long long)D4;
  if (tid >= total) return;
  int d4 = (int)(tid % D4);
  long long k = tid / D4;
  int s = src ? src[k] : (int)k;
  int d = dst[k];
  float sc = scale ? scale[s] : 1.0f;
  const float4 x = *reinterpret_cast<const float4*>(X + ((long long)s * D4 + d4) * 4);
  float* y = Y + ((long long)d * D4 + d4) * 4;
  atomicAdd(y + 0, x.x * sc);
  atomicAdd(y + 1, x.y * sc);
  atomicAdd(y + 2, x.z * sc);
  atomicAdd(y + 3, x.w * sc);
}

// ---------------- row-scale (+ optional relu) ----------------
__global__ __launch_bounds__(256) void k_scale_rows(float* __restrict__ X,
                                                    const float* __restrict__ s,
                                                    long long M, int D4, int relu) {
  long long tid = (long long)blockIdx.x * 256 + threadIdx.x;
  if (tid >= M * (long long)D4) return;
  int d4 = (int)(tid % D4);
  long long r = tid / D4;
  float sv = s[r];
  float4 v = *reinterpret_cast<float4*>(X + (r * D4 + d4) * 4);
  v.x *= sv; v.y *= sv; v.z *= sv; v.w *= sv;
  if (relu) {
    v.x = fmaxf(v.x, 0.0f); v.y = fmaxf(v.y, 0.0f);
    v.z = fmaxf(v.z, 0.0f); v.w = fmaxf(v.w, 0.0f);
  }
  *reinterpret_cast<float4*>(X + (r * D4 + d4) * 4) = v;
}

// ---------------- GEMM with optional concat + row-gather on A ----------------
// C[M][BN] = concat(Aa[idxa? idxa[r]: r][0:Ka], Ab[r][0:Kb]) @ W[(Ka+Kb)][BN] + bias
// block = 256 threads, tile BM x BN, K-chunks of 64 staged in LDS.
template <int BM, int BN>
__global__ __launch_bounds__(256) void k_gemm_cat(const float* __restrict__ Aa,
                                                  const int* __restrict__ idxa, int Ka,
                                                  const float* __restrict__ Ab, int Kb,
                                                  const float* __restrict__ W,
                                                  const float* __restrict__ bias,
                                                  float* __restrict__ C, int M) {
  constexpr int KC = 64;
  constexpr int CG = BN / 8;        // column groups (8 cols per thread)
  constexpr int RG = 256 / CG;      // row groups
  constexpr int R = BM / RG;        // rows per thread
  constexpr int AS = KC + 4;        // padded A stride (272B rows, 16B aligned)

  __shared__ float As[BM][AS];
  __shared__ float Ws[KC][BN];

  const int t = threadIdx.x;
  const int cg = t % CG;
  const int rg = t / CG;
  const int blockRow = blockIdx.x * BM;
  const int K = Ka + Kb;

  float acc[R][8];
  {
    float4 b0 = *reinterpret_cast<const float4*>(bias + cg * 8);
    float4 b1 = *reinterpret_cast<const float4*>(bias + cg * 8 + 4);
#pragma unroll
    for (int r = 0; r < R; r++) {
      acc[r][0] = b0.x; acc[r][1] = b0.y; acc[r][2] = b0.z; acc[r][3] = b0.w;
      acc[r][4] = b1.x; acc[r][5] = b1.y; acc[r][6] = b1.z; acc[r][7] = b1.w;
    }
  }

  for (int kc = 0; kc < K; kc += KC) {
    // stage A chunk: BM x KC
    constexpr int ALOADS = BM * KC / 4 / 256;
#pragma unroll
    for (int i = 0; i < ALOADS; i++) {
      int fl = t + i * 256;
      int row = fl / (KC / 4);
      int k4 = fl % (KC / 4);
      int gr = blockRow + row;
      int gk = kc + k4 * 4;
      float4 v = make_float4(0.f, 0.f, 0.f, 0.f);
      if (gr < M) {
        if (gk < Ka) {
          long long ar = idxa ? (long long)idxa[gr] : (long long)gr;
          v = *reinterpret_cast<const float4*>(Aa + ar * Ka + gk);
        } else {
          v = *reinterpret_cast<const float4*>(Ab + (long long)gr * Kb + (gk - Ka));
        }
      }
      *reinterpret_cast<float4*>(&As[row][k4 * 4]) = v;
    }
    // stage W chunk: KC x BN
    constexpr int WLOADS = KC * BN / 4 / 256;
#pragma unroll
    for (int i = 0; i < WLOADS; i++) {
      int fl = t + i * 256;
      int wr = fl / (BN / 4);
      int wc = fl % (BN / 4);
      *reinterpret_cast<float4*>(&Ws[wr][wc * 4]) =
          *reinterpret_cast<const float4*>(W + (long long)(kc + wr) * BN + wc * 4);
    }
    __syncthreads();

#pragma unroll
    for (int kk = 0; kk < KC; kk++) {
      float4 w0 = *reinterpret_cast<float4*>(&Ws[kk][cg * 8]);
      float4 w1 = *reinterpret_cast<float4*>(&Ws[kk][cg * 8 + 4]);
#pragma unroll
      for (int r = 0; r < R; r++) {
        float a = As[rg * R + r][kk];
        acc[r][0] += a * w0.x; acc[r][1] += a * w0.y;
        acc[r][2] += a * w0.z; acc[r][3] += a * w0.w;
        acc[r][4] += a * w1.x; acc[r][5] += a * w1.y;
        acc[r][6] += a * w1.z; acc[r][7] += a * w1.w;
      }
    }
    __syncthreads();
  }

#pragma unroll
  for (int r = 0; r < R; r++) {
    int gr = blockRow + rg * R + r;
    if (gr < M) {
      float4 o0 = make_float4(acc[r][0], acc[r][1], acc[r][2], acc[r][3]);
      float4 o1 = make_float4(acc[r][4], acc[r][5], acc[r][6], acc[r][7]);
      *reinterpret_cast<float4*>(C + (long long)gr * BN + cg * 8) = o0;
      *reinterpret_cast<float4*>(C + (long long)gr * BN + cg * 8 + 4) = o1;
    }
  }
}

// ---------------- launch ----------------
extern "C" void kernel_launch(void* const* d_in, const int* in_sizes, int n_in,
                              void* d_out, int out_size, void* d_ws, size_t ws_size,
                              hipStream_t stream) {
  const float* X  = (const float*)d_in[0];
  const float* W0 = (const float*)d_in[1];
  const float* b0 = (const float*)d_in[2];
  const float* W1 = (const float*)d_in[3];
  const float* b1 = (const float*)d_in[4];
  const float* W2 = (const float*)d_in[5];
  const float* b2 = (const float*)d_in[6];
  const float* W3 = (const float*)d_in[7];
  const float* b3 = (const float*)d_in[8];
  const float* W4 = (const float*)d_in[9];
  const float* b4 = (const float*)d_in[10];
  const int* H0v = (const int*)d_in[11];
  const int* H0e = (const int*)d_in[12];
  const int* H1v = (const int*)d_in[13];
  const int* H1e = (const int*)d_in[14];
  const int* H2v = (const int*)d_in[15];
  const int* H2e = (const int*)d_in[16];
  const int* as0 = (const int*)d_in[17];
  const int* as1 = (const int*)d_in[18];
  float* out = (float*)d_out;
  float* ws = (float*)d_ws;

  // -------- workspace layout (floats), accumulators first (one memset) -----
  size_t off = 0;
  auto alloc = [&](size_t n) { size_t o = off; off += (n + 63) & ~(size_t)63; return o; };
  const size_t o_h0  = alloc((size_t)CN0 * 128);
  const size_t o_Y0  = alloc((size_t)CE0 * 128);
  const size_t o_Xc1 = alloc((size_t)CN1 * 128);
  const size_t o_h1  = alloc((size_t)CN1 * 128);
  const size_t o_Y1  = alloc((size_t)CE1 * 128);
  const size_t o_Y1b = alloc((size_t)CE1 * 128);
  const size_t o_Xc2 = alloc((size_t)CN2 * 128);
  const size_t o_z2  = alloc((size_t)CN2 * 128);
  const size_t o_Y2  = alloc((size_t)CE2 * 128);
  const size_t o_z3  = alloc((size_t)CN1 * 128);
  const size_t o_Y0b = alloc((size_t)CE0 * 64);
  const size_t o_dV0 = alloc(CN0);
  const size_t o_dE0 = alloc(CE0);
  const size_t o_dV1 = alloc(CN1);
  const size_t o_dE1 = alloc(CE1);
  const size_t o_dV2 = alloc(CN2);
  const size_t o_dE2 = alloc(CE2);
  const size_t o_cnt0 = alloc(CN1);
  const size_t o_cnt1 = alloc(CN2);
  const size_t accEnd = off;                       // everything above must be zeroed
  const size_t o_t0 = alloc((size_t)CN0 * 128);    // reused for t3, t4
  const size_t o_t1 = alloc((size_t)CN1 * 128);    // reused for t2
  const size_t o_t3 = o_t0;
  const size_t o_t4 = o_t0;
  const size_t o_t2 = o_t1;
  (void)ws_size; (void)in_sizes; (void)n_in; (void)out_size;

  // -------- zero accumulators + output --------
  hipMemsetAsync(ws, 0, accEnd * sizeof(float), stream);
  hipMemsetAsync(d_out, 0, (size_t)CN0 * 64 * sizeof(float), stream);

  // -------- degrees / normalizations --------
  k_degree2<<<cdiv_i(CNNZ0, 256), 256, 0, stream>>>(H0v, H0e, ws + o_dV0, ws + o_dE0, CNNZ0);
  k_degree2<<<cdiv_i(CNNZ1, 256), 256, 0, stream>>>(H1v, H1e, ws + o_dV1, ws + o_dE1, CNNZ1);
  k_degree2<<<cdiv_i(CNNZ2, 256), 256, 0, stream>>>(H2v, H2e, ws + o_dV2, ws + o_dE2, CNNZ2);
  k_count<<<cdiv_i(CN0, 256), 256, 0, stream>>>(as0, ws + o_cnt0, CN0);
  k_count<<<cdiv_i(CN1, 256), 256, 0, stream>>>(as1, ws + o_cnt1, CN1);
  k_recip<<<cdiv_i(CN0, 256), 256, 0, stream>>>(ws + o_dV0, CN0, 0);
  k_recip<<<cdiv_i(CE0, 256), 256, 0, stream>>>(ws + o_dE0, CE0, 1);
  k_recip<<<cdiv_i(CN1, 256), 256, 0, stream>>>(ws + o_dV1, CN1, 0);
  k_recip<<<cdiv_i(CE1, 256), 256, 0, stream>>>(ws + o_dE1, CE1, 1);
  k_recip<<<cdiv_i(CN2, 256), 256, 0, stream>>>(ws + o_dV2, CN2, 0);
  k_recip<<<cdiv_i(CE2, 256), 256, 0, stream>>>(ws + o_dE2, CE2, 1);
  k_recip<<<cdiv_i(CN1, 256), 256, 0, stream>>>(ws + o_cnt0, CN1, 1);
  k_recip<<<cdiv_i(CN2, 256), 256, 0, stream>>>(ws + o_cnt1, CN2, 1);

  // -------- level 0: h0 = relu(L0(X@W0+b0)) --------
  k_gemm_cat<64, 128><<<cdiv_i(CN0, 64), 256, 0, stream>>>(X, nullptr, 128, nullptr, 0, W0, b0, ws + o_t0, CN0);
  k_scatter<<<cdiv_i((long long)CNNZ0 * 32, 256), 256, 0, stream>>>(ws + o_t0, H0v, H0e, ws + o_dV0, ws + o_Y0, CNNZ0, 32);
  k_scatter<<<cdiv_i((long long)CNNZ0 * 32, 256), 256, 0, stream>>>(ws + o_Y0, H0e, H0v, ws + o_dE0, ws + o_h0, CNNZ0, 32);
  k_scale_rows<<<cdiv_i((long long)CN0 * 32, 256), 256, 0, stream>>>(ws + o_h0, ws + o_dV0, CN0, 32, 1);

  // -------- pool0: Xc1 = mean over clusters --------
  k_scatter<<<cdiv_i((long long)CN0 * 32, 256), 256, 0, stream>>>(ws + o_h0, nullptr, as0, nullptr, ws + o_Xc1, CN0, 32);
  k_scale_rows<<<cdiv_i((long long)CN1 * 32, 256), 256, 0, stream>>>(ws + o_Xc1, ws + o_cnt0, CN1, 32, 0);

  // -------- level 1: h1 = relu(L1(Xc1@W1+b1)) --------
  k_gemm_cat<64, 128><<<cdiv_i(CN1, 64), 256, 0, stream>>>(ws + o_Xc1, nullptr, 128, nullptr, 0, W1, b1, ws + o_t1, CN1);
  k_scatter<<<cdiv_i((long long)CNNZ1 * 32, 256), 256, 0, stream>>>(ws + o_t1, H1v, H1e, ws + o_dV1, ws + o_Y1, CNNZ1, 32);
  k_scatter<<<cdiv_i((long long)CNNZ1 * 32, 256), 256, 0, stream>>>(ws + o_Y1, H1e, H1v, ws + o_dE1, ws + o_h1, CNNZ1, 32);
  k_scale_rows<<<cdiv_i((long long)CN1 * 32, 256), 256, 0, stream>>>(ws + o_h1, ws + o_dV1, CN1, 32, 1);

  // -------- pool1: Xc2 --------
  k_scatter<<<cdiv_i((long long)CN1 * 32, 256), 256, 0, stream>>>(ws + o_h1, nullptr, as1, nullptr, ws + o_Xc2, CN1, 32);
  k_scale_rows<<<cdiv_i((long long)CN2 * 32, 256), 256, 0, stream>>>(ws + o_Xc2, ws + o_cnt1, CN2, 32, 0);

  // -------- level 2: z2 = relu(L2(Xc2@W2+b2)) --------
  k_gemm_cat<64, 128><<<cdiv_i(CN2, 64), 256, 0, stream>>>(ws + o_Xc2, nullptr, 128, nullptr, 0, W2, b2, ws + o_t2, CN2);
  k_scatter<<<cdiv_i((long long)CNNZ2 * 32, 256), 256, 0, stream>>>(ws + o_t2, H2v, H2e, ws + o_dV2, ws + o_Y2, CNNZ2, 32);
  k_scatter<<<cdiv_i((long long)CNNZ2 * 32, 256), 256, 0, stream>>>(ws + o_Y2, H2e, H2v, ws + o_dE2, ws + o_z2, CNNZ2, 32);
  k_scale_rows<<<cdiv_i((long long)CN2 * 32, 256), 256, 0, stream>>>(ws + o_z2, ws + o_dV2, CN2, 32, 1);

  // -------- up1: z3 = relu(L1(concat(z2[assign1], h1)@W3+b3)) --------
  k_gemm_cat<64, 128><<<cdiv_i(CN1, 64), 256, 0, stream>>>(ws + o_z2, as1, 128, ws + o_h1, 128, W3, b3, ws + o_t3, CN1);
  k_scatter<<<cdiv_i((long long)CNNZ1 * 32, 256), 256, 0, stream>>>(ws + o_t3, H1v, H1e, ws + o_dV1, ws + o_Y1b, CNNZ1, 32);
  k_scatter<<<cdiv_i((long long)CNNZ1 * 32, 256), 256, 0, stream>>>(ws + o_Y1b, H1e, H1v, ws + o_dE1, ws + o_z3, CNNZ1, 32);
  k_scale_rows<<<cdiv_i((long long)CN1 * 32, 256), 256, 0, stream>>>(ws + o_z3, ws + o_dV1, CN1, 32, 1);

  // -------- up0 + final: out = L0(concat(z3[assign0], h0)@W4+b4) --------
  k_gemm_cat<128, 64><<<cdiv_i(CN0, 128), 256, 0, stream>>>(ws + o_z3, as0, 128, ws + o_h0, 128, W4, b4, ws + o_t4, CN0);
  k_scatter<<<cdiv_i((long long)CNNZ0 * 16, 256), 256, 0, stream>>>(ws + o_t4, H0v, H0e, ws + o_dV0, ws + o_Y0b, CNNZ0, 16);
  k_scatter<<<cdiv_i((long long)CNNZ0 * 16, 256), 256, 0, stream>>>(ws + o_Y0b, H0e, H0v, ws + o_dE0, out, CNNZ0, 16);
  k_scale_rows<<<cdiv_i((long long)CN0 * 16, 256), 256, 0, stream>>>(out, ws + o_dV0, CN0, 16, 0);
}

// Round 6
// 1581.127 us; speedup vs baseline: 7.5359x; 7.5359x over previous
//
#include <hip/hip_runtime.h>

// ---------------- problem constants ----------------
#define CN0 100000
#define CN1 25000
#define CN2 6250
#define CE0 20000
#define CE1 5000
#define CE2 1250
#define CNNZ0 1600000
#define CNNZ1 400000
#define CNNZ2 100000
// D_IN = D_H = 128, D_OUT = 64

static inline int cdiv_i(long long a, long long b) { return (int)((a + b - 1) / b); }

// ---------------- histogram (1 or 2 index arrays) ----------------
__global__ __launch_bounds__(256) void k_hist2(const int* __restrict__ a,
                                               const int* __restrict__ b,
                                               int* __restrict__ ha,
                                               int* __restrict__ hb, int n) {
  int i = blockIdx.x * 256 + threadIdx.x;
  if (i < n) {
    atomicAdd(ha + a[i], 1);
    if (b) atomicAdd(hb + b[i], 1);
  }
}

// ---------------- single-block exclusive scan + norm ----------------
// rowstart[i] = sum(hist[0..i-1]); rowstart[n] = total; cursor = copy
// norm[i] = hist[i]>0 ? (mode0 ? 1/sqrt : 1/x) : 0
__global__ __launch_bounds__(1024) void k_scan(const int* __restrict__ hist,
                                               int* __restrict__ rowstart,
                                               int* __restrict__ cursor,
                                               float* __restrict__ norm,
                                               int n, int mode) {
  __shared__ int wsum[16];
  __shared__ int wpre[16];
  __shared__ int chunk_total;
  __shared__ int carry;
  const int lane = threadIdx.x & 63;
  const int wid = threadIdx.x >> 6;
  if (threadIdx.x == 0) carry = 0;
  __syncthreads();
  for (int base = 0; base < n; base += 1024) {
    int i = base + threadIdx.x;
    int v = (i < n) ? hist[i] : 0;
    int x = v;
#pragma unroll
    for (int off = 1; off < 64; off <<= 1) {
      int t = __shfl_up(x, off);
      if (lane >= off) x += t;
    }
    if (lane == 63) wsum[wid] = x;
    __syncthreads();
    if (threadIdx.x == 0) {
      int s = 0;
      for (int w = 0; w < 16; w++) { wpre[w] = s; s += wsum[w]; }
      chunk_total = s;
    }
    __syncthreads();
    if (i < n) {
      int excl = carry + wpre[wid] + x - v;
      rowstart[i] = excl;
      cursor[i] = excl;
      if (norm) {
        float c = (float)v;
        norm[i] = (v > 0) ? ((mode == 0) ? (1.0f / sqrtf(c)) : (1.0f / c)) : 0.0f;
      }
    }
    __syncthreads();
    if (threadIdx.x == 0) carry += chunk_total;
    __syncthreads();
  }
  if (threadIdx.x == 0) rowstart[n] = carry;
}

// ---------------- counting-sort scatter: both directions ----------------
__global__ __launch_bounds__(256) void k_sortpair(const int* __restrict__ vi,
                                                  const int* __restrict__ ei,
                                                  int* __restrict__ cur_v,
                                                  int* __restrict__ cur_e,
                                                  int* __restrict__ e_by_v,
                                                  int* __restrict__ v_by_e, int n) {
  int i = blockIdx.x * 256 + threadIdx.x;
  if (i < n) {
    int v = vi[i], e = ei[i];
    int p = atomicAdd(cur_e + e, 1);
    v_by_e[p] = v;
    int q = atomicAdd(cur_v + v, 1);
    e_by_v[q] = e;
  }
}

__global__ __launch_bounds__(256) void k_sortself(const int* __restrict__ asg,
                                                  int* __restrict__ cur,
                                                  int* __restrict__ r_by_c, int n) {
  int i = blockIdx.x * 256 + threadIdx.x;
  if (i < n) {
    int p = atomicAdd(cur + asg[i], 1);
    r_by_c[p] = i;
  }
}

// ---------------- gather-based segment sum ----------------
// out[w][:] = outscale(w) * sum_{j in [rowstart[w],rowstart[w+1])}
//                 in[srcids[j]][:] * (inscale ? inscale[srcids[j]] : 1)
// one wave per destination row; D4 float4s per row; 64/D4 groups per wave.
template <int D4>
__global__ __launch_bounds__(256) void k_gather(const float* __restrict__ in,
                                                const int* __restrict__ rowstart,
                                                const int* __restrict__ srcids,
                                                const float* __restrict__ inscale,
                                                const float* __restrict__ outscale,
                                                float* __restrict__ out,
                                                int nseg, int relu) {
  constexpr int G = 64 / D4;
  const int w = blockIdx.x * 4 + (threadIdx.x >> 6);
  if (w >= nseg) return;
  const int lane = threadIdx.x & 63;
  const int g = lane / D4;
  const int d4 = lane % D4;
  const int start = rowstart[w];
  const int end = rowstart[w + 1];
  float4 acc = make_float4(0.f, 0.f, 0.f, 0.f);
  for (int j = start + g; j < end; j += G) {
    int s = srcids[j];
    float sc = inscale ? inscale[s] : 1.0f;
    float4 v = *reinterpret_cast<const float4*>(in + ((long long)s * D4 + d4) * 4);
    acc.x += v.x * sc;
    acc.y += v.y * sc;
    acc.z += v.z * sc;
    acc.w += v.w * sc;
  }
#pragma unroll
  for (int off = D4; off < 64; off <<= 1) {
    acc.x += __shfl_xor(acc.x, off);
    acc.y += __shfl_xor(acc.y, off);
    acc.z += __shfl_xor(acc.z, off);
    acc.w += __shfl_xor(acc.w, off);
  }
  if (g == 0) {
    float os = outscale ? outscale[w] : 1.0f;
    acc.x *= os; acc.y *= os; acc.z *= os; acc.w *= os;
    if (relu) {
      acc.x = fmaxf(acc.x, 0.f); acc.y = fmaxf(acc.y, 0.f);
      acc.z = fmaxf(acc.z, 0.f); acc.w = fmaxf(acc.w, 0.f);
    }
    *reinterpret_cast<float4*>(out + ((long long)w * D4 + d4) * 4) = acc;
  }
}

// ---------------- GEMM with optional concat + row-gather on A ----------------
template <int BM, int BN>
__global__ __launch_bounds__(256) void k_gemm_cat(const float* __restrict__ Aa,
                                                  const int* __restrict__ idxa, int Ka,
                                                  const float* __restrict__ Ab, int Kb,
                                                  const float* __restrict__ W,
                                                  const float* __restrict__ bias,
                                                  float* __restrict__ C, int M) {
  constexpr int KC = 64;
  constexpr int CG = BN / 8;
  constexpr int RG = 256 / CG;
  constexpr int R = BM / RG;
  constexpr int AS = KC + 4;

  __shared__ float As[BM][AS];
  __shared__ float Ws[KC][BN];

  const int t = threadIdx.x;
  const int cg = t % CG;
  const int rg = t / CG;
  const int blockRow = blockIdx.x * BM;
  const int K = Ka + Kb;

  float acc[R][8];
  {
    float4 b0 = *reinterpret_cast<const float4*>(bias + cg * 8);
    float4 b1 = *reinterpret_cast<const float4*>(bias + cg * 8 + 4);
#pragma unroll
    for (int r = 0; r < R; r++) {
      acc[r][0] = b0.x; acc[r][1] = b0.y; acc[r][2] = b0.z; acc[r][3] = b0.w;
      acc[r][4] = b1.x; acc[r][5] = b1.y; acc[r][6] = b1.z; acc[r][7] = b1.w;
    }
  }

  for (int kc = 0; kc < K; kc += KC) {
    constexpr int ALOADS = BM * KC / 4 / 256;
#pragma unroll
    for (int i = 0; i < ALOADS; i++) {
      int fl = t + i * 256;
      int row = fl / (KC / 4);
      int k4 = fl % (KC / 4);
      int gr = blockRow + row;
      int gk = kc + k4 * 4;
      float4 v = make_float4(0.f, 0.f, 0.f, 0.f);
      if (gr < M) {
        if (gk < Ka) {
          long long ar = idxa ? (long long)idxa[gr] : (long long)gr;
          v = *reinterpret_cast<const float4*>(Aa + ar * Ka + gk);
        } else {
          v = *reinterpret_cast<const float4*>(Ab + (long long)gr * Kb + (gk - Ka));
        }
      }
      *reinterpret_cast<float4*>(&As[row][k4 * 4]) = v;
    }
    constexpr int WLOADS = KC * BN / 4 / 256;
#pragma unroll
    for (int i = 0; i < WLOADS; i++) {
      int fl = t + i * 256;
      int wr = fl / (BN / 4);
      int wc = fl % (BN / 4);
      *reinterpret_cast<float4*>(&Ws[wr][wc * 4]) =
          *reinterpret_cast<const float4*>(W + (long long)(kc + wr) * BN + wc * 4);
    }
    __syncthreads();

#pragma unroll
    for (int kk = 0; kk < KC; kk++) {
      float4 w0 = *reinterpret_cast<float4*>(&Ws[kk][cg * 8]);
      float4 w1 = *reinterpret_cast<float4*>(&Ws[kk][cg * 8 + 4]);
#pragma unroll
      for (int r = 0; r < R; r++) {
        float a = As[rg * R + r][kk];
        acc[r][0] += a * w0.x; acc[r][1] += a * w0.y;
        acc[r][2] += a * w0.z; acc[r][3] += a * w0.w;
        acc[r][4] += a * w1.x; acc[r][5] += a * w1.y;
        acc[r][6] += a * w1.z; acc[r][7] += a * w1.w;
      }
    }
    __syncthreads();
  }

#pragma unroll
  for (int r = 0; r < R; r++) {
    int gr = blockRow + rg * R + r;
    if (gr < M) {
      float4 o0 = make_float4(acc[r][0], acc[r][1], acc[r][2], acc[r][3]);
      float4 o1 = make_float4(acc[r][4], acc[r][5], acc[r][6], acc[r][7]);
      *reinterpret_cast<float4*>(C + (long long)gr * BN + cg * 8) = o0;
      *reinterpret_cast<float4*>(C + (long long)gr * BN + cg * 8 + 4) = o1;
    }
  }
}

// ---------------- launch ----------------
extern "C" void kernel_launch(void* const* d_in, const int* in_sizes, int n_in,
                              void* d_out, int out_size, void* d_ws, size_t ws_size,
                              hipStream_t stream) {
  const float* X  = (const float*)d_in[0];
  const float* W0 = (const float*)d_in[1];
  const float* b0 = (const float*)d_in[2];
  const float* W1 = (const float*)d_in[3];
  const float* b1 = (const float*)d_in[4];
  const float* W2 = (const float*)d_in[5];
  const float* b2 = (const float*)d_in[6];
  const float* W3 = (const float*)d_in[7];
  const float* b3 = (const float*)d_in[8];
  const float* W4 = (const float*)d_in[9];
  const float* b4 = (const float*)d_in[10];
  const int* H0v = (const int*)d_in[11];
  const int* H0e = (const int*)d_in[12];
  const int* H1v = (const int*)d_in[13];
  const int* H1e = (const int*)d_in[14];
  const int* H2v = (const int*)d_in[15];
  const int* H2e = (const int*)d_in[16];
  const int* as0 = (const int*)d_in[17];
  const int* as1 = (const int*)d_in[18];
  float* out = (float*)d_out;
  (void)in_sizes; (void)n_in; (void)out_size; (void)ws_size;

  char* base = (char*)d_ws;
  size_t off = 0;
  auto alloci = [&](size_t n) -> int* {
    int* p = (int*)(base + off);
    off = (off + n * 4 + 255) & ~(size_t)255;
    return p;
  };
  auto allocf = [&](size_t n) -> float* {
    float* p = (float*)(base + off);
    off = (off + n * 4 + 255) & ~(size_t)255;
    return p;
  };

  // ---- histograms + cursors (must be zeroed) ----
  int* hv0 = alloci(CN0); int* he0 = alloci(CE0);
  int* hv1 = alloci(CN1); int* he1 = alloci(CE1);
  int* hv2 = alloci(CN2); int* he2 = alloci(CE2);
  int* hc0 = alloci(CN1); int* hc1 = alloci(CN2);
  int* cv0 = alloci(CN0); int* ce0 = alloci(CE0);
  int* cv1 = alloci(CN1); int* ce1 = alloci(CE1);
  int* cv2 = alloci(CN2); int* ce2 = alloci(CE2);
  int* cc0 = alloci(CN1); int* cc1 = alloci(CN2);
  const size_t zero_bytes = off;
  // ---- rowstarts ----
  int* rv0 = alloci(CN0 + 1); int* re0 = alloci(CE0 + 1);
  int* rv1 = alloci(CN1 + 1); int* re1 = alloci(CE1 + 1);
  int* rv2 = alloci(CN2 + 1); int* re2 = alloci(CE2 + 1);
  int* rc0 = alloci(CN1 + 1); int* rc1 = alloci(CN2 + 1);
  // ---- sorted source ids ----
  int* vbe0 = alloci(CNNZ0); int* ebv0 = alloci(CNNZ0);
  int* vbe1 = alloci(CNNZ1); int* ebv1 = alloci(CNNZ1);
  int* vbe2 = alloci(CNNZ2); int* ebv2 = alloci(CNNZ2);
  int* rbc0 = alloci(CN0);   int* rbc1 = alloci(CN1);
  // ---- normalization vectors ----
  float* dvis0 = allocf(CN0); float* dei0 = allocf(CE0);
  float* dvis1 = allocf(CN1); float* dei1 = allocf(CE1);
  float* dvis2 = allocf(CN2); float* dei2 = allocf(CE2);
  float* ic0 = allocf(CN1);   float* ic1 = allocf(CN2);
  // ---- float buffers (slot-reused) ----
  float* A  = allocf((size_t)CN0 * 128);  // t0, then h0
  float* B  = allocf((size_t)CE0 * 128);  // Y0, then Y0b (D=64)
  float* Cc = allocf((size_t)CN1 * 128);  // Xc1, then t3
  float* D  = allocf((size_t)CN1 * 128);  // t1, then h1
  float* E  = allocf((size_t)CE1 * 128);  // Y1, then Y1b
  float* F  = allocf((size_t)CN2 * 128);  // Xc2, then z2
  float* G  = allocf((size_t)CN2 * 128);  // t2
  float* Hh = allocf((size_t)CE2 * 128);  // Y2
  float* I  = allocf((size_t)CN1 * 128);  // z3
  float* J  = allocf((size_t)CN0 * 64);   // t4

  hipMemsetAsync(d_ws, 0, zero_bytes, stream);

  // ---- build CSR-style structures ----
  k_hist2<<<cdiv_i(CNNZ0, 256), 256, 0, stream>>>(H0v, H0e, hv0, he0, CNNZ0);
  k_hist2<<<cdiv_i(CNNZ1, 256), 256, 0, stream>>>(H1v, H1e, hv1, he1, CNNZ1);
  k_hist2<<<cdiv_i(CNNZ2, 256), 256, 0, stream>>>(H2v, H2e, hv2, he2, CNNZ2);
  k_hist2<<<cdiv_i(CN0, 256), 256, 0, stream>>>(as0, nullptr, hc0, nullptr, CN0);
  k_hist2<<<cdiv_i(CN1, 256), 256, 0, stream>>>(as1, nullptr, hc1, nullptr, CN1);

  k_scan<<<1, 1024, 0, stream>>>(hv0, rv0, cv0, dvis0, CN0, 0);
  k_scan<<<1, 1024, 0, stream>>>(he0, re0, ce0, dei0, CE0, 1);
  k_scan<<<1, 1024, 0, stream>>>(hv1, rv1, cv1, dvis1, CN1, 0);
  k_scan<<<1, 1024, 0, stream>>>(he1, re1, ce1, dei1, CE1, 1);
  k_scan<<<1, 1024, 0, stream>>>(hv2, rv2, cv2, dvis2, CN2, 0);
  k_scan<<<1, 1024, 0, stream>>>(he2, re2, ce2, dei2, CE2, 1);
  k_scan<<<1, 1024, 0, stream>>>(hc0, rc0, cc0, ic0, CN1, 1);
  k_scan<<<1, 1024, 0, stream>>>(hc1, rc1, cc1, ic1, CN2, 1);

  k_sortpair<<<cdiv_i(CNNZ0, 256), 256, 0, stream>>>(H0v, H0e, cv0, ce0, ebv0, vbe0, CNNZ0);
  k_sortpair<<<cdiv_i(CNNZ1, 256), 256, 0, stream>>>(H1v, H1e, cv1, ce1, ebv1, vbe1, CNNZ1);
  k_sortpair<<<cdiv_i(CNNZ2, 256), 256, 0, stream>>>(H2v, H2e, cv2, ce2, ebv2, vbe2, CNNZ2);
  k_sortself<<<cdiv_i(CN0, 256), 256, 0, stream>>>(as0, cc0, rbc0, CN0);
  k_sortself<<<cdiv_i(CN1, 256), 256, 0, stream>>>(as1, cc1, rbc1, CN1);

  // ---- level 0: h0 = relu(L0(X@W0+b0)) ----
  k_gemm_cat<64, 128><<<cdiv_i(CN0, 64), 256, 0, stream>>>(X, nullptr, 128, nullptr, 0, W0, b0, A, CN0);
  k_gather<32><<<cdiv_i(CE0, 4), 256, 0, stream>>>(A, re0, vbe0, dvis0, dei0, B, CE0, 0);
  k_gather<32><<<cdiv_i(CN0, 4), 256, 0, stream>>>(B, rv0, ebv0, nullptr, dvis0, A, CN0, 1);  // h0 -> A

  // ---- pool0: Xc1 ----
  k_gather<32><<<cdiv_i(CN1, 4), 256, 0, stream>>>(A, rc0, rbc0, nullptr, ic0, Cc, CN1, 0);

  // ---- level 1: h1 = relu(L1(Xc1@W1+b1)) ----
  k_gemm_cat<64, 128><<<cdiv_i(CN1, 64), 256, 0, stream>>>(Cc, nullptr, 128, nullptr, 0, W1, b1, D, CN1);
  k_gather<32><<<cdiv_i(CE1, 4), 256, 0, stream>>>(D, re1, vbe1, dvis1, dei1, E, CE1, 0);
  k_gather<32><<<cdiv_i(CN1, 4), 256, 0, stream>>>(E, rv1, ebv1, nullptr, dvis1, D, CN1, 1);  // h1 -> D

  // ---- pool1: Xc2 ----
  k_gather<32><<<cdiv_i(CN2, 4), 256, 0, stream>>>(D, rc1, rbc1, nullptr, ic1, F, CN2, 0);

  // ---- level 2: z2 = relu(L2(Xc2@W2+b2)) ----
  k_gemm_cat<64, 128><<<cdiv_i(CN2, 64), 256, 0, stream>>>(F, nullptr, 128, nullptr, 0, W2, b2, G, CN2);
  k_gather<32><<<cdiv_i(CE2, 4), 256, 0, stream>>>(G, re2, vbe2, dvis2, dei2, Hh, CE2, 0);
  k_gather<32><<<cdiv_i(CN2, 4), 256, 0, stream>>>(Hh, rv2, ebv2, nullptr, dvis2, F, CN2, 1); // z2 -> F

  // ---- up1: z3 = relu(L1(concat(z2[as1], h1)@W3+b3)) ----
  k_gemm_cat<64, 128><<<cdiv_i(CN1, 64), 256, 0, stream>>>(F, as1, 128, D, 128, W3, b3, Cc, CN1); // t3 -> Cc
  k_gather<32><<<cdiv_i(CE1, 4), 256, 0, stream>>>(Cc, re1, vbe1, dvis1, dei1, E, CE1, 0);
  k_gather<32><<<cdiv_i(CN1, 4), 256, 0, stream>>>(E, rv1, ebv1, nullptr, dvis1, I, CN1, 1);  // z3 -> I

  // ---- up0 + final: out = L0(concat(z3[as0], h0)@W4+b4) ----
  k_gemm_cat<128, 64><<<cdiv_i(CN0, 128), 256, 0, stream>>>(I, as0, 128, A, 128, W4, b4, J, CN0);
  k_gather<16><<<cdiv_i(CE0, 4), 256, 0, stream>>>(J, re0, vbe0, dvis0, dei0, B, CE0, 0);
  k_gather<16><<<cdiv_i(CN0, 4), 256, 0, stream>>>(B, rv0, ebv0, nullptr, dvis0, out, CN0, 0);
}

// Round 9
// 1108.071 us; speedup vs baseline: 10.7532x; 1.4269x over previous
//
#include <hip/hip_runtime.h>

// ---------------- problem constants ----------------
#define CN0 100000
#define CN1 25000
#define CN2 6250
#define CE0 20000
#define CE1 5000
#define CE2 1250
#define CNNZ0 1600000
#define CNNZ1 400000
#define CNNZ2 100000
// D_IN = D_H = 128, D_OUT = 64

static inline int cdiv_i(long long a, long long b) { return (int)((a + b - 1) / b); }

// ---- block-wide exclusive scan over in[0..N), N<=512, 256 threads ----
__device__ inline void block_exscan(const int* in, int* out, int N, int* tmp) {
  __syncthreads();
  const int t = threadIdx.x, lane = t & 63, wid = t >> 6;
  const int i0 = 2 * t, i1 = i0 + 1;
  int c0 = (i0 < N) ? in[i0] : 0;
  int c1 = (i1 < N) ? in[i1] : 0;
  int p = c0 + c1, ip = p;
#pragma unroll
  for (int off = 1; off < 64; off <<= 1) {
    int u = __shfl_up(ip, off);
    if (lane >= off) ip += u;
  }
  if (lane == 63) tmp[wid] = ip;
  __syncthreads();
  int woff = 0;
  for (int w = 0; w < wid; w++) woff += tmp[w];
  int base = woff + ip - p;
  if (i0 < N) out[i0] = base;
  if (i1 < N) out[i1] = base + c0;
  __syncthreads();
}

// ---------------- LDS-histogram bucket counts (1 or 2 key arrays) ----------------
__global__ __launch_bounds__(256) void k_bhist(const int* __restrict__ ka,
                                               const int* __restrict__ kb,
                                               int n, int sba, int sbb,
                                               int nba, int nbb,
                                               int* __restrict__ ga,
                                               int* __restrict__ gb) {
  __shared__ int lha[512], lhb[512];
  const int t = threadIdx.x;
  for (int j = t; j < nba; j += 256) lha[j] = 0;
  if (kb) for (int j = t; j < nbb; j += 256) lhb[j] = 0;
  __syncthreads();
  int beg = blockIdx.x * 8192;
  int end = min(beg + 8192, n);
  for (int i = beg + t; i < end; i += 256) {
    atomicAdd(lha + (ka[i] >> sba), 1);
    if (kb) atomicAdd(lhb + (kb[i] >> sbb), 1);
  }
  __syncthreads();
  for (int j = t; j < nba; j += 256) if (lha[j]) atomicAdd(ga + j, lha[j]);
  if (kb) for (int j = t; j < nbb; j += 256) if (lhb[j]) atomicAdd(gb + j, lhb[j]);
}

// ---------------- bucket starts (16-aligned) + cursor init, 7 arrays ----------------
struct ScanDesc { const int* cnt; int* start; int* cur; int nb; };
struct ScanDescs { ScanDesc d[7]; };
__global__ __launch_bounds__(256) void k_bscan_multi(ScanDescs s) {
  __shared__ int la[512], lex[512], tmp[4];
  ScanDesc d = s.d[blockIdx.x];
  const int t = threadIdx.x;
  for (int j = t; j < d.nb; j += 256) la[j] = (d.cnt[j] + 15) & ~15;
  block_exscan(la, lex, d.nb, tmp);
  for (int j = t; j < d.nb; j += 256) { d.start[j] = lex[j]; d.cur[j] = lex[j]; }
}

// ---------------- phase A: block-run bucket scatter of packed (key|payload) ----------
__global__ __launch_bounds__(256) void k_bscatter(const int* __restrict__ ka,
                                                  const int* __restrict__ kb,
                                                  int n, int sba, int pba,
                                                  int sbb, int pbb,
                                                  int nba, int nbb,
                                                  int* __restrict__ curA,
                                                  int* __restrict__ curB,
                                                  unsigned* __restrict__ packA,
                                                  unsigned* __restrict__ packB) {
  __shared__ int lha[512], basea[512], lhb[512], baseb[512];
  const int t = threadIdx.x;
  for (int j = t; j < nba; j += 256) lha[j] = 0;
  if (kb) for (int j = t; j < nbb; j += 256) lhb[j] = 0;
  __syncthreads();
  int beg = blockIdx.x * 8192;
  int end = min(beg + 8192, n);
  for (int i = beg + t; i < end; i += 256) {
    atomicAdd(lha + (ka[i] >> sba), 1);
    if (kb) atomicAdd(lhb + (kb[i] >> sbb), 1);
  }
  __syncthreads();
  for (int j = t; j < nba; j += 256) {
    int c = lha[j];
    basea[j] = c ? atomicAdd(curA + j, c) : 0;
    lha[j] = 0;
  }
  if (kb) for (int j = t; j < nbb; j += 256) {
    int c = lhb[j];
    baseb[j] = c ? atomicAdd(curB + j, c) : 0;
    lhb[j] = 0;
  }
  __syncthreads();
  for (int i = beg + t; i < end; i += 256) {
    int a = ka[i];
    int pa = kb ? kb[i] : i;
    int ba = a >> sba;
    int pos = basea[ba] + atomicAdd(lha + ba, 1);
    packA[pos] = ((unsigned)a << pba) | (unsigned)pa;
    if (kb) {
      int b = kb[i];
      int bb = b >> sbb;
      int posb = baseb[bb] + atomicAdd(lhb + bb, 1);
      packB[posb] = ((unsigned)b << pbb) | (unsigned)a;
    }
  }
}

// ---------------- phase B: per-bucket LDS counting sort, IN PLACE -------------------
// pack is consumed (packed key|payload) and overwritten with grouped payload ints.
// bucket staged in LDS (max bucket ~5.5K << 8448). rs/ren/norm emitted per key.
#define STAGE_CAP 8448
__global__ __launch_bounds__(256) void k_lsort(unsigned* __restrict__ pack,
                                               const int* __restrict__ bstart,
                                               const int* __restrict__ bcnt,
                                               int localn, int pbits, int nkey,
                                               int* __restrict__ rs,
                                               int* __restrict__ ren,
                                               float* __restrict__ norm, int mode) {
  __shared__ int lh[256], lex[256], lcur[256], tmp[4];
  __shared__ unsigned stage[STAGE_CAP];
  const int t = threadIdx.x;
  const int b = blockIdx.x;
  const int start = bstart[b];
  const int cnt = min(bcnt[b], STAGE_CAP);
  for (int j = t; j < localn; j += 256) { lh[j] = 0; lcur[j] = 0; }
  __syncthreads();
  const unsigned lmask = (unsigned)localn - 1u;
  const unsigned pmask = (1u << pbits) - 1u;
  for (int i = t; i < cnt; i += 256) {
    unsigned pk = pack[start + i];
    stage[i] = pk;
    atomicAdd(lh + (int)((pk >> pbits) & lmask), 1);
  }
  block_exscan(lh, lex, localn, tmp);
  for (int i = t; i < cnt; i += 256) {
    unsigned pk = stage[i];
    int lk = (int)((pk >> pbits) & lmask);
    int pos = lex[lk] + atomicAdd(lcur + lk, 1);
    pack[start + pos] = pk & pmask;
  }
  for (int j = t; j < localn; j += 256) {
    int key = b * localn + j;
    if (key < nkey) {
      int c = lh[j];
      int r = start + lex[j];
      rs[key] = r;
      ren[key] = r + c;
      norm[key] = (c > 0) ? (mode ? 1.0f / (float)c : 1.0f / sqrtf((float)c)) : 0.0f;
    }
  }
}

// ---------------- small old path (assign1 only) ----------------
__global__ __launch_bounds__(256) void k_hist2(const int* __restrict__ a,
                                               int* __restrict__ ha, int n) {
  int i = blockIdx.x * 256 + threadIdx.x;
  if (i < n) atomicAdd(ha + a[i], 1);
}

__global__ __launch_bounds__(1024) void k_scan(const int* __restrict__ hist,
                                               int* __restrict__ rowstart,
                                               int* __restrict__ cursor,
                                               float* __restrict__ norm,
                                               int n, int mode) {
  __shared__ int wsum[16];
  __shared__ int wpre[16];
  __shared__ int chunk_total;
  __shared__ int carry;
  const int lane = threadIdx.x & 63;
  const int wid = threadIdx.x >> 6;
  if (threadIdx.x == 0) carry = 0;
  __syncthreads();
  for (int base = 0; base < n; base += 1024) {
    int i = base + threadIdx.x;
    int v = (i < n) ? hist[i] : 0;
    int x = v;
#pragma unroll
    for (int off = 1; off < 64; off <<= 1) {
      int t = __shfl_up(x, off);
      if (lane >= off) x += t;
    }
    if (lane == 63) wsum[wid] = x;
    __syncthreads();
    if (threadIdx.x == 0) {
      int s = 0;
      for (int w = 0; w < 16; w++) { wpre[w] = s; s += wsum[w]; }
      chunk_total = s;
    }
    __syncthreads();
    if (i < n) {
      int excl = carry + wpre[wid] + x - v;
      rowstart[i] = excl;
      cursor[i] = excl;
      float c = (float)v;
      norm[i] = (v > 0) ? ((mode == 0) ? (1.0f / sqrtf(c)) : (1.0f / c)) : 0.0f;
    }
    __syncthreads();
    if (threadIdx.x == 0) carry += chunk_total;
    __syncthreads();
  }
  if (threadIdx.x == 0) rowstart[n] = carry;
}

__global__ __launch_bounds__(256) void k_sortself(const int* __restrict__ asg,
                                                  int* __restrict__ cur,
                                                  int* __restrict__ r_by_c, int n) {
  int i = blockIdx.x * 256 + threadIdx.x;
  if (i < n) {
    int p = atomicAdd(cur + asg[i], 1);
    r_by_c[p] = i;
  }
}

// ---------------- gather-based segment sum ----------------
template <int D4>
__global__ __launch_bounds__(256) void k_gather(const float* __restrict__ in,
                                                const int* __restrict__ rs,
                                                const int* __restrict__ ren,
                                                const int* __restrict__ srcids,
                                                const float* __restrict__ inscale,
                                                const float* __restrict__ outscale,
                                                float* __restrict__ out,
                                                int nseg, int relu) {
  constexpr int G = 64 / D4;
  const int w = blockIdx.x * 4 + (threadIdx.x >> 6);
  if (w >= nseg) return;
  const int lane = threadIdx.x & 63;
  const int g = lane / D4;
  const int d4 = lane % D4;
  const int start = rs[w];
  const int end = ren[w];
  float4 acc = make_float4(0.f, 0.f, 0.f, 0.f);
  for (int j = start + g; j < end; j += G) {
    int s = srcids[j];
    float sc = inscale ? inscale[s] : 1.0f;
    float4 v = *reinterpret_cast<const float4*>(in + ((long long)s * D4 + d4) * 4);
    acc.x += v.x * sc;
    acc.y += v.y * sc;
    acc.z += v.z * sc;
    acc.w += v.w * sc;
  }
#pragma unroll
  for (int off = D4; off < 64; off <<= 1) {
    acc.x += __shfl_xor(acc.x, off);
    acc.y += __shfl_xor(acc.y, off);
    acc.z += __shfl_xor(acc.z, off);
    acc.w += __shfl_xor(acc.w, off);
  }
  if (g == 0) {
    float os = outscale ? outscale[w] : 1.0f;
    acc.x *= os; acc.y *= os; acc.z *= os; acc.w *= os;
    if (relu) {
      acc.x = fmaxf(acc.x, 0.f); acc.y = fmaxf(acc.y, 0.f);
      acc.z = fmaxf(acc.z, 0.f); acc.w = fmaxf(acc.w, 0.f);
    }
    *reinterpret_cast<float4*>(out + ((long long)w * D4 + d4) * 4) = acc;
  }
}

// ---------------- GEMM with optional concat + row-gather on A ----------------
template <int BM, int BN>
__global__ __launch_bounds__(256) void k_gemm_cat(const float* __restrict__ Aa,
                                                  const int* __restrict__ idxa, int Ka,
                                                  const float* __restrict__ Ab, int Kb,
                                                  const float* __restrict__ W,
                                                  const float* __restrict__ bias,
                                                  float* __restrict__ C, int M) {
  constexpr int KC = 64;
  constexpr int CG = BN / 8;
  constexpr int RG = 256 / CG;
  constexpr int R = BM / RG;
  constexpr int AS = KC + 4;

  __shared__ float As[BM][AS];
  __shared__ float Ws[KC][BN];

  const int t = threadIdx.x;
  const int cg = t % CG;
  const int rg = t / CG;
  const int blockRow = blockIdx.x * BM;
  const int K = Ka + Kb;

  float acc[R][8];
  {
    float4 b0 = *reinterpret_cast<const float4*>(bias + cg * 8);
    float4 b1 = *reinterpret_cast<const float4*>(bias + cg * 8 + 4);
#pragma unroll
    for (int r = 0; r < R; r++) {
      acc[r][0] = b0.x; acc[r][1] = b0.y; acc[r][2] = b0.z; acc[r][3] = b0.w;
      acc[r][4] = b1.x; acc[r][5] = b1.y; acc[r][6] = b1.z; acc[r][7] = b1.w;
    }
  }

  for (int kc = 0; kc < K; kc += KC) {
    constexpr int ALOADS = BM * KC / 4 / 256;
#pragma unroll
    for (int i = 0; i < ALOADS; i++) {
      int fl = t + i * 256;
      int row = fl / (KC / 4);
      int k4 = fl % (KC / 4);
      int gr = blockRow + row;
      int gk = kc + k4 * 4;
      float4 v = make_float4(0.f, 0.f, 0.f, 0.f);
      if (gr < M) {
        if (gk < Ka) {
          long long ar = idxa ? (long long)idxa[gr] : (long long)gr;
          v = *reinterpret_cast<const float4*>(Aa + ar * Ka + gk);
        } else {
          v = *reinterpret_cast<const float4*>(Ab + (long long)gr * Kb + (gk - Ka));
        }
      }
      *reinterpret_cast<float4*>(&As[row][k4 * 4]) = v;
    }
    constexpr int WLOADS = KC * BN / 4 / 256;
#pragma unroll
    for (int i = 0; i < WLOADS; i++) {
      int fl = t + i * 256;
      int wr = fl / (BN / 4);
      int wc = fl % (BN / 4);
      *reinterpret_cast<float4*>(&Ws[wr][wc * 4]) =
          *reinterpret_cast<const float4*>(W + (long long)(kc + wr) * BN + wc * 4);
    }
    __syncthreads();

#pragma unroll
    for (int kk = 0; kk < KC; kk++) {
      float4 w0 = *reinterpret_cast<float4*>(&Ws[kk][cg * 8]);
      float4 w1 = *reinterpret_cast<float4*>(&Ws[kk][cg * 8 + 4]);
#pragma unroll
      for (int r = 0; r < R; r++) {
        float a = As[rg * R + r][kk];
        acc[r][0] += a * w0.x; acc[r][1] += a * w0.y;
        acc[r][2] += a * w0.z; acc[r][3] += a * w0.w;
        acc[r][4] += a * w1.x; acc[r][5] += a * w1.y;
        acc[r][6] += a * w1.z; acc[r][7] += a * w1.w;
      }
    }
    __syncthreads();
  }

#pragma unroll
  for (int r = 0; r < R; r++) {
    int gr = blockRow + rg * R + r;
    if (gr < M) {
      float4 o0 = make_float4(acc[r][0], acc[r][1], acc[r][2], acc[r][3]);
      float4 o1 = make_float4(acc[r][4], acc[r][5], acc[r][6], acc[r][7]);
      *reinterpret_cast<float4*>(C + (long long)gr * BN + cg * 8) = o0;
      *reinterpret_cast<float4*>(C + (long long)gr * BN + cg * 8 + 4) = o1;
    }
  }
}

// ---------------- launch ----------------
extern "C" void kernel_launch(void* const* d_in, const int* in_sizes, int n_in,
                              void* d_out, int out_size, void* d_ws, size_t ws_size,
                              hipStream_t stream) {
  const float* X  = (const float*)d_in[0];
  const float* W0 = (const float*)d_in[1];
  const float* b0 = (const float*)d_in[2];
  const float* W1 = (const float*)d_in[3];
  const float* b1 = (const float*)d_in[4];
  const float* W2 = (const float*)d_in[5];
  const float* b2 = (const float*)d_in[6];
  const float* W3 = (const float*)d_in[7];
  const float* b3 = (const float*)d_in[8];
  const float* W4 = (const float*)d_in[9];
  const float* b4 = (const float*)d_in[10];
  const int* H0v = (const int*)d_in[11];
  const int* H0e = (const int*)d_in[12];
  const int* H1v = (const int*)d_in[13];
  const int* H1e = (const int*)d_in[14];
  const int* H2v = (const int*)d_in[15];
  const int* H2e = (const int*)d_in[16];
  const int* as0 = (const int*)d_in[17];
  const int* as1 = (const int*)d_in[18];
  float* out = (float*)d_out;
  (void)in_sizes; (void)n_in; (void)out_size; (void)ws_size;

  const int NBE0 = 313, NBV0 = 391, NBE1 = 313, NBV1 = 391;
  const int NBE2 = 313, NBV2 = 391, NBC0 = 391;
  const int PAD = 8192;  // 16-aligned bucket layout spans N + <15*NB < PAD

  char* base = (char*)d_ws;
  size_t off = 0;
  auto alloci = [&](size_t n) -> int* {
    int* p = (int*)(base + off);
    off = (off + n * 4 + 255) & ~(size_t)255;
    return p;
  };
  auto allocf = [&](size_t n) -> float* {
    float* p = (float*)(base + off);
    off = (off + n * 4 + 255) & ~(size_t)255;
    return p;
  };
  auto allocu = [&](size_t n) -> unsigned* {
    unsigned* p = (unsigned*)(base + off);
    off = (off + n * 4 + 255) & ~(size_t)255;
    return p;
  };

  // ---- zeroed region: bucket histograms + as1 hist ----
  int* gcE0 = alloci(NBE0); int* gcV0 = alloci(NBV0);
  int* gcE1 = alloci(NBE1); int* gcV1 = alloci(NBV1);
  int* gcE2 = alloci(NBE2); int* gcV2 = alloci(NBV2);
  int* gcC0 = alloci(NBC0);
  int* hc1  = alloci(CN2);
  const size_t zero_bytes = off;
  // ---- bucket starts + cursors ----
  int* bsE0 = alloci(NBE0); int* cuE0 = alloci(NBE0);
  int* bsV0 = alloci(NBV0); int* cuV0 = alloci(NBV0);
  int* bsE1 = alloci(NBE1); int* cuE1 = alloci(NBE1);
  int* bsV1 = alloci(NBV1); int* cuV1 = alloci(NBV1);
  int* bsE2 = alloci(NBE2); int* cuE2 = alloci(NBE2);
  int* bsV2 = alloci(NBV2); int* cuV2 = alloci(NBV2);
  int* bsC0 = alloci(NBC0); int* cuC0 = alloci(NBC0);
  // ---- rs/ren/norm per side ----
  int* rsE0 = alloci(CE0); int* reE0 = alloci(CE0); float* dei0  = allocf(CE0);
  int* rsV0 = alloci(CN0); int* reV0 = alloci(CN0); float* dvis0 = allocf(CN0);
  int* rsE1 = alloci(CE1); int* reE1 = alloci(CE1); float* dei1  = allocf(CE1);
  int* rsV1 = alloci(CN1); int* reV1 = alloci(CN1); float* dvis1 = allocf(CN1);
  int* rsE2 = alloci(CE2); int* reE2 = alloci(CE2); float* dei2  = allocf(CE2);
  int* rsV2 = alloci(CN2); int* reV2 = alloci(CN2); float* dvis2 = allocf(CN2);
  int* rsC0 = alloci(CN1); int* reC0 = alloci(CN1); float* ic0   = allocf(CN1);
  // ---- packed buffers (padded; sorted IN PLACE to payload ints by k_lsort) ----
  unsigned* pkE0 = allocu(CNNZ0 + PAD); unsigned* pkV0 = allocu(CNNZ0 + PAD);
  unsigned* pkE1 = allocu(CNNZ1 + PAD); unsigned* pkV1 = allocu(CNNZ1 + PAD);
  unsigned* pkE2 = allocu(CNNZ2 + PAD); unsigned* pkV2 = allocu(CNNZ2 + PAD);
  unsigned* pkC0 = allocu(CN0 + PAD);
  int* vbe0 = (int*)pkE0; int* ebv0 = (int*)pkV0;
  int* vbe1 = (int*)pkE1; int* ebv1 = (int*)pkV1;
  int* vbe2 = (int*)pkE2; int* ebv2 = (int*)pkV2;
  int* rbc0 = (int*)pkC0;
  // ---- as1 old path ----
  int* rc1 = alloci(CN2 + 1); int* cc1 = alloci(CN2); float* ic1 = allocf(CN2);
  int* rbc1 = alloci(CN1);
  // ---- float buffers (slot-reused; J aliases Cc+D which are dead by then) ----
  float* A  = allocf((size_t)CN0 * 128);  // t0, then h0
  float* B  = allocf((size_t)CE0 * 128);  // Y0, then Y0b (D=64)
  float* P  = allocf((size_t)CN0 * 64);   // = CN1*128 * 2
  float* Cc = P;                          // Xc1, then t3
  float* D  = P + (size_t)CN1 * 128;      // t1, then h1
  float* J  = P;                          // t4 (Cc,D dead at final gemm)
  float* E  = allocf((size_t)CE1 * 128);  // Y1, then Y1b
  float* F  = allocf((size_t)CN2 * 128);  // Xc2, then z2
  float* G  = allocf((size_t)CN2 * 128);  // t2
  float* Hh = allocf((size_t)CE2 * 128);  // Y2
  float* I  = allocf((size_t)CN1 * 128);  // z3

  hipMemsetAsync(d_ws, 0, zero_bytes, stream);

  // ---- bucket histograms ----
  k_bhist<<<cdiv_i(CNNZ0, 8192), 256, 0, stream>>>(H0e, H0v, CNNZ0, 6, 8, NBE0, NBV0, gcE0, gcV0);
  k_bhist<<<cdiv_i(CNNZ1, 8192), 256, 0, stream>>>(H1e, H1v, CNNZ1, 4, 6, NBE1, NBV1, gcE1, gcV1);
  k_bhist<<<cdiv_i(CNNZ2, 8192), 256, 0, stream>>>(H2e, H2v, CNNZ2, 2, 4, NBE2, NBV2, gcE2, gcV2);
  k_bhist<<<cdiv_i(CN0, 8192), 256, 0, stream>>>(as0, nullptr, CN0, 6, 0, NBC0, 0, gcC0, nullptr);
  k_hist2<<<cdiv_i(CN1, 256), 256, 0, stream>>>(as1, hc1, CN1);

  // ---- bucket starts + cursors ----
  ScanDescs sd;
  sd.d[0] = {gcE0, bsE0, cuE0, NBE0};
  sd.d[1] = {gcV0, bsV0, cuV0, NBV0};
  sd.d[2] = {gcE1, bsE1, cuE1, NBE1};
  sd.d[3] = {gcV1, bsV1, cuV1, NBV1};
  sd.d[4] = {gcE2, bsE2, cuE2, NBE2};
  sd.d[5] = {gcV2, bsV2, cuV2, NBV2};
  sd.d[6] = {gcC0, bsC0, cuC0, NBC0};
  k_bscan_multi<<<7, 256, 0, stream>>>(sd);
  k_scan<<<1, 1024, 0, stream>>>(hc1, rc1, cc1, ic1, CN2, 1);

  // ---- phase A: bucket scatter (packed) ----
  k_bscatter<<<cdiv_i(CNNZ0, 8192), 256, 0, stream>>>(H0e, H0v, CNNZ0, 6, 17, 8, 15, NBE0, NBV0, cuE0, cuV0, pkE0, pkV0);
  k_bscatter<<<cdiv_i(CNNZ1, 8192), 256, 0, stream>>>(H1e, H1v, CNNZ1, 4, 15, 6, 13, NBE1, NBV1, cuE1, cuV1, pkE1, pkV1);
  k_bscatter<<<cdiv_i(CNNZ2, 8192), 256, 0, stream>>>(H2e, H2v, CNNZ2, 2, 13, 4, 11, NBE2, NBV2, cuE2, cuV2, pkE2, pkV2);
  k_bscatter<<<cdiv_i(CN0, 8192), 256, 0, stream>>>(as0, nullptr, CN0, 6, 17, 0, 0, NBC0, 0, cuC0, nullptr, pkC0, nullptr);
  k_sortself<<<cdiv_i(CN1, 256), 256, 0, stream>>>(as1, cc1, rbc1, CN1);

  // ---- phase B: per-bucket in-place counting sort + rs/ren/norm ----
  k_lsort<<<NBE0, 256, 0, stream>>>(pkE0, bsE0, gcE0, 64, 17, CE0, rsE0, reE0, dei0, 1);
  k_lsort<<<NBV0, 256, 0, stream>>>(pkV0, bsV0, gcV0, 256, 15, CN0, rsV0, reV0, dvis0, 0);
  k_lsort<<<NBE1, 256, 0, stream>>>(pkE1, bsE1, gcE1, 16, 15, CE1, rsE1, reE1, dei1, 1);
  k_lsort<<<NBV1, 256, 0, stream>>>(pkV1, bsV1, gcV1, 64, 13, CN1, rsV1, reV1, dvis1, 0);
  k_lsort<<<NBE2, 256, 0, stream>>>(pkE2, bsE2, gcE2, 4, 13, CE2, rsE2, reE2, dei2, 1);
  k_lsort<<<NBV2, 256, 0, stream>>>(pkV2, bsV2, gcV2, 16, 11, CN2, rsV2, reV2, dvis2, 0);
  k_lsort<<<NBC0, 256, 0, stream>>>(pkC0, bsC0, gcC0, 64, 17, CN1, rsC0, reC0, ic0, 1);

  // ---- level 0: h0 = relu(L0(X@W0+b0)) ----
  k_gemm_cat<64, 128><<<cdiv_i(CN0, 64), 256, 0, stream>>>(X, nullptr, 128, nullptr, 0, W0, b0, A, CN0);
  k_gather<32><<<cdiv_i(CE0, 4), 256, 0, stream>>>(A, rsE0, reE0, vbe0, dvis0, dei0, B, CE0, 0);
  k_gather<32><<<cdiv_i(CN0, 4), 256, 0, stream>>>(B, rsV0, reV0, ebv0, nullptr, dvis0, A, CN0, 1);  // h0 -> A

  // ---- pool0: Xc1 ----
  k_gather<32><<<cdiv_i(CN1, 4), 256, 0, stream>>>(A, rsC0, reC0, rbc0, nullptr, ic0, Cc, CN1, 0);

  // ---- level 1: h1 = relu(L1(Xc1@W1+b1)) ----
  k_gemm_cat<64, 128><<<cdiv_i(CN1, 64), 256, 0, stream>>>(Cc, nullptr, 128, nullptr, 0, W1, b1, D, CN1);
  k_gather<32><<<cdiv_i(CE1, 4), 256, 0, stream>>>(D, rsE1, reE1, vbe1, dvis1, dei1, E, CE1, 0);
  k_gather<32><<<cdiv_i(CN1, 4), 256, 0, stream>>>(E, rsV1, reV1, ebv1, nullptr, dvis1, D, CN1, 1);  // h1 -> D

  // ---- pool1: Xc2 ----
  k_gather<32><<<cdiv_i(CN2, 4), 256, 0, stream>>>(D, rc1, rc1 + 1, rbc1, nullptr, ic1, F, CN2, 0);

  // ---- level 2: z2 = relu(L2(Xc2@W2+b2)) ----
  k_gemm_cat<64, 128><<<cdiv_i(CN2, 64), 256, 0, stream>>>(F, nullptr, 128, nullptr, 0, W2, b2, G, CN2);
  k_gather<32><<<cdiv_i(CE2, 4), 256, 0, stream>>>(G, rsE2, reE2, vbe2, dvis2, dei2, Hh, CE2, 0);
  k_gather<32><<<cdiv_i(CN2, 4), 256, 0, stream>>>(Hh, rsV2, reV2, ebv2, nullptr, dvis2, F, CN2, 1); // z2 -> F

  // ---- up1: z3 = relu(L1(concat(z2[as1], h1)@W3+b3)) ----
  k_gemm_cat<64, 128><<<cdiv_i(CN1, 64), 256, 0, stream>>>(F, as1, 128, D, 128, W3, b3, Cc, CN1); // t3 -> Cc
  k_gather<32><<<cdiv_i(CE1, 4), 256, 0, stream>>>(Cc, rsE1, reE1, vbe1, dvis1, dei1, E, CE1, 0);
  k_gather<32><<<cdiv_i(CN1, 4), 256, 0, stream>>>(E, rsV1, reV1, ebv1, nullptr, dvis1, I, CN1, 1);  // z3 -> I

  // ---- up0 + final: out = L0(concat(z3[as0], h0)@W4+b4) ----
  k_gemm_cat<128, 64><<<cdiv_i(CN0, 128), 256, 0, stream>>>(I, as0, 128, A, 128, W4, b4, J, CN0);
  k_gather<16><<<cdiv_i(CE0, 4), 256, 0, stream>>>(J, rsE0, reE0, vbe0, dvis0, dei0, B, CE0, 0);
  k_gather<16><<<cdiv_i(CN0, 4), 256, 0, stream>>>(B, rsV0, reV0, ebv0, nullptr, dvis0, out, CN0, 0);
}